// Round 1
// baseline (1255.838 us; speedup 1.0000x reference)
//
#include <hip/hip_runtime.h>
#include <hip/hip_bf16.h>
#include <math.h>

// ---- problem constants ----
#define S_    2048
#define FF_   1024
#define NC_   7
#define NF_   7168
#define MAXK  819
#define KP_   896           // padded K dim (7*128)
#define Z_    14            // B*NUM_CATS
#define NEGV  (-10000.0f)

typedef __attribute__((ext_vector_type(8))) short bf16x8;
typedef __attribute__((ext_vector_type(4))) float f32x4;

__device__ __forceinline__ void gload_lds16(const void* g, void* l) {
  __builtin_amdgcn_global_load_lds((const __attribute__((address_space(1))) unsigned int*)g,
                                   (__attribute__((address_space(3))) unsigned int*)l, 16, 0, 0);
}

__device__ __forceinline__ float gelu_exact(float x) {
  return 0.5f * x * (1.0f + erff(x * 0.70710678118654752f));
}

// ---------------- split f32 -> (hi,lo) bf16 ----------------
__global__ __launch_bounds__(256) void k_split(const float* __restrict__ x,
                                               __hip_bfloat16* __restrict__ hi,
                                               __hip_bfloat16* __restrict__ lo, int n) {
  int i = blockIdx.x * 256 + threadIdx.x;
  int stride = gridDim.x * 256;
  for (; i < n; i += stride) {
    float v = x[i];
    __hip_bfloat16 h = __float2bfloat16(v);
    hi[i] = h;
    lo[i] = __float2bfloat16(v - __bfloat162float(h));
  }
}

// ---------------- cast f32 -> bf16 ----------------
__global__ __launch_bounds__(256) void k_cast(const float* __restrict__ x,
                                              __hip_bfloat16* __restrict__ y, int n) {
  int i = blockIdx.x * 256 + threadIdx.x;
  int stride = gridDim.x * 256;
  for (; i < n; i += stride) y[i] = __float2bfloat16(x[i]);
}

// ---------------- MFMA GEMM (C[m,n] = sum_k A[m,k]*B[n,k]), 128x128 tile ----------------
// MODE 0: single product (A0,B0)            -- bf16 GEMM
// MODE 1: dual products (A0,B0)+(A1,B1)     -- fused accumulate
// MODE 2: split3 (A0=Ah,A1=Al,B0=Bh,B1=Bl): Ah*Bh + Ah*Bl + Al*Bh  (~f32 accuracy)
template<int MODE, bool OBF16>
__global__ __launch_bounds__(256) void k_gemm(
    const __hip_bfloat16* __restrict__ A0, const __hip_bfloat16* __restrict__ A1,
    const __hip_bfloat16* __restrict__ B0, const __hip_bfloat16* __restrict__ B1,
    void* __restrict__ Cv, const float* __restrict__ bias,
    int K, long strideA, long strideB, int bmod7, long strideC,
    int ldc, int Mstore, int Nstore)
{
  constexpr int NMAT = (MODE == 0) ? 2 : 4;
  __shared__ __align__(16) char smem[NMAT * 8192];
  const int tid = threadIdx.x;
  const int z = blockIdx.z;
  const int m0 = blockIdx.x * 128, n0 = blockIdx.y * 128;
  const long aoff = (long)z * strideA;
  const long boff = (long)(bmod7 ? (z % 7) : z) * strideB;
  const __hip_bfloat16* pA0 = A0 + aoff;
  const __hip_bfloat16* pA1 = (MODE == 0) ? A0 : A1 + aoff;
  const __hip_bfloat16* pB0 = B0 + boff;
  const __hip_bfloat16* pB1 = (MODE == 0) ? B0 : B1 + boff;
  char* ldsA0 = smem;
  char* ldsA1 = (MODE == 0) ? smem : smem + 8192;
  char* ldsB0 = (MODE == 0) ? smem + 8192 : smem + 16384;
  char* ldsB1 = (MODE == 0) ? smem : smem + 24576;

  const int w = tid >> 6, l = tid & 63;
  const int wr = w >> 1, wc = w & 1;
  const int lr = l & 15, kh = l >> 4;

  f32x4 acc[4][4];
  #pragma unroll
  for (int i = 0; i < 4; ++i)
    #pragma unroll
    for (int j = 0; j < 4; ++j)
      #pragma unroll
      for (int r = 0; r < 4; ++r) acc[i][j][r] = 0.0f;

  const int nk = K >> 5;
  for (int kt = 0; kt < nk; ++kt) {
    const int k0 = kt << 5;
    #pragma unroll
    for (int is = 0; is < 2; ++is) {
      int idx = is * 256 + tid;
      int row = idx >> 2, kq = idx & 3;
      long gcol = (long)k0 + kq * 8;
      gload_lds16(pA0 + (long)(m0 + row) * K + gcol, ldsA0 + idx * 16);
      if (MODE) gload_lds16(pA1 + (long)(m0 + row) * K + gcol, ldsA1 + idx * 16);
      gload_lds16(pB0 + (long)(n0 + row) * K + gcol, ldsB0 + idx * 16);
      if (MODE) gload_lds16(pB1 + (long)(n0 + row) * K + gcol, ldsB1 + idx * 16);
    }
    __syncthreads();   // compiler drains vmcnt before barrier

    bf16x8 a0[4], b0[4], a1[4], b1[4];
    #pragma unroll
    for (int mi = 0; mi < 4; ++mi) {
      int ro = (wr * 64 + mi * 16 + lr) * 64 + kh * 16;
      a0[mi] = *(const bf16x8*)(ldsA0 + ro);
      if (MODE) a1[mi] = *(const bf16x8*)(ldsA1 + ro);
    }
    #pragma unroll
    for (int ni = 0; ni < 4; ++ni) {
      int ro = (wc * 64 + ni * 16 + lr) * 64 + kh * 16;
      b0[ni] = *(const bf16x8*)(ldsB0 + ro);
      if (MODE) b1[ni] = *(const bf16x8*)(ldsB1 + ro);
    }
    #pragma unroll
    for (int mi = 0; mi < 4; ++mi)
      #pragma unroll
      for (int ni = 0; ni < 4; ++ni) {
        acc[mi][ni] = __builtin_amdgcn_mfma_f32_16x16x32_bf16(a0[mi], b0[ni], acc[mi][ni], 0, 0, 0);
        if (MODE == 1)
          acc[mi][ni] = __builtin_amdgcn_mfma_f32_16x16x32_bf16(a1[mi], b1[ni], acc[mi][ni], 0, 0, 0);
        if (MODE == 2) {
          acc[mi][ni] = __builtin_amdgcn_mfma_f32_16x16x32_bf16(a0[mi], b1[ni], acc[mi][ni], 0, 0, 0);
          acc[mi][ni] = __builtin_amdgcn_mfma_f32_16x16x32_bf16(a1[mi], b0[ni], acc[mi][ni], 0, 0, 0);
        }
      }
    __syncthreads();
  }

  const long coff = (long)z * strideC;
  #pragma unroll
  for (int mi = 0; mi < 4; ++mi)
    #pragma unroll
    for (int ni = 0; ni < 4; ++ni) {
      int n = n0 + wc * 64 + ni * 16 + lr;
      if (n >= Nstore) continue;
      float badd = bias ? bias[n] : 0.0f;
      #pragma unroll
      for (int r = 0; r < 4; ++r) {
        int m = m0 + wr * 64 + mi * 16 + kh * 4 + r;
        if (m >= Mstore) continue;
        float v = acc[mi][ni][r] + badd;
        if (OBF16) ((__hip_bfloat16*)Cv)[coff + (long)m * ldc + n] = __float2bfloat16(v);
        else       ((float*)Cv)[coff + (long)m * ldc + n] = v;
      }
    }
}

// ---------------- GELU + LayerNorm, in-place f32, row width = VPT*256 ----------------
template<int VPT>
__global__ __launch_bounds__(256) void k_gelu_ln(float* __restrict__ h,
                                                 const float* __restrict__ g,
                                                 const float* __restrict__ beta) {
  const int N = VPT * 256;
  long base = (long)blockIdx.x * N;
  float v[VPT];
  float s = 0.f, s2 = 0.f;
  #pragma unroll
  for (int i = 0; i < VPT; ++i) {
    float x = h[base + i * 256 + threadIdx.x];
    float ge = gelu_exact(x);
    v[i] = ge; s += ge; s2 += ge * ge;
  }
  __shared__ float red0[4], red1[4];
  for (int off = 32; off; off >>= 1) { s += __shfl_xor(s, off); s2 += __shfl_xor(s2, off); }
  int w = threadIdx.x >> 6;
  if ((threadIdx.x & 63) == 0) { red0[w] = s; red1[w] = s2; }
  __syncthreads();
  s  = red0[0] + red0[1] + red0[2] + red0[3];
  s2 = red1[0] + red1[1] + red1[2] + red1[3];
  float mu  = s / (float)N;
  float var = s2 / (float)N - mu * mu;
  float inv = 1.0f / sqrtf(var + 1e-5f);
  #pragma unroll
  for (int i = 0; i < VPT; ++i) {
    int c = i * 256 + threadIdx.x;
    h[base + c] = (v[i] - mu) * inv * g[c] + beta[c];
  }
}

// ---------------- GELU+LN over 7168, write bf16 transposed to [z=b*7+n][k][f] ----------------
__global__ __launch_bounds__(256) void k_gelu_ln_cats(const float* __restrict__ h,
                                                      const float* __restrict__ g,
                                                      const float* __restrict__ beta,
                                                      __hip_bfloat16* __restrict__ outp) {
  const int VPT = 28;                       // 7168/256
  int r = blockIdx.x;                       // 0..2*KP-1
  int b = r / KP_, k = r % KP_;
  const float* row = h + (long)r * NF_;
  float v[VPT];
  float s = 0.f, s2 = 0.f;
  #pragma unroll
  for (int i = 0; i < VPT; ++i) {
    float x = row[i * 256 + threadIdx.x];
    float ge = gelu_exact(x);
    v[i] = ge; s += ge; s2 += ge * ge;
  }
  __shared__ float red0[4], red1[4];
  for (int off = 32; off; off >>= 1) { s += __shfl_xor(s, off); s2 += __shfl_xor(s2, off); }
  int w = threadIdx.x >> 6;
  if ((threadIdx.x & 63) == 0) { red0[w] = s; red1[w] = s2; }
  __syncthreads();
  s  = red0[0] + red0[1] + red0[2] + red0[3];
  s2 = red1[0] + red1[1] + red1[2] + red1[3];
  float mu  = s / (float)NF_;
  float var = s2 / (float)NF_ - mu * mu;
  float inv = 1.0f / sqrtf(var + 1e-5f);
  #pragma unroll
  for (int i = 0; i < VPT; ++i) {
    int c = i * 256 + threadIdx.x;
    int n = c >> 10, f = c & 1023;
    float val = (v[i] - mu) * inv * g[c] + beta[c];
    outp[((long)((b * NC_ + n) * KP_ + k)) * FF_ + f] = __float2bfloat16(val);
  }
}

// ---------------- row dot: out[r] = X[r,:1024].w + b0 ----------------
__global__ __launch_bounds__(256) void k_rowdot(const float* __restrict__ X,
                                                const float* __restrict__ wv,
                                                const float* __restrict__ b0,
                                                float* __restrict__ outp, int rows) {
  int w = threadIdx.x >> 6, l = threadIdx.x & 63;
  int row = blockIdx.x * 4 + w;
  if (row >= rows) return;
  const float4* xp = (const float4*)(X + (long)row * 1024);
  const float4* wp = (const float4*)wv;
  float acc = 0.f;
  #pragma unroll
  for (int q = 0; q < 4; ++q) {
    float4 a = xp[l + 64 * q], b = wp[l + 64 * q];
    acc += a.x * b.x + a.y * b.y + a.z * b.z + a.w * b.w;
  }
  for (int off = 32; off; off >>= 1) acc += __shfl_xor(acc, off);
  if (l == 0) outp[row] = acc + b0[0];
}

// ---------------- banded scores: band[b][s][j] = s2[b,s].e[b,s+j] + sm + em ----------------
__global__ __launch_bounds__(256) void k_band(const float* __restrict__ s2m,
                                              const float* __restrict__ em,
                                              const float* __restrict__ smv,
                                              const float* __restrict__ emv,
                                              float* __restrict__ band) {
  __shared__ float s2row[1024];
  int bs = blockIdx.x;                 // b*2048+s
  const float* sp = s2m + (long)bs * 1024;
  for (int i = threadIdx.x; i < 1024; i += 256) s2row[i] = sp[i];
  __syncthreads();
  int b = bs >> 11, s = bs & 2047;
  int w = threadIdx.x >> 6, l = threadIdx.x & 63;
  for (int j = w; j < 32; j += 4) {
    int t = s + j;
    float val = -3.0e38f;
    if (j < 30 && t < S_) {
      const float4* ep = (const float4*)(em + ((long)(b << 11) + t) * 1024);
      const float4* zp = (const float4*)s2row;
      float acc = 0.f;
      #pragma unroll
      for (int q = 0; q < 4; ++q) {
        float4 a = ep[l + 64 * q], c = zp[l + 64 * q];
        acc += a.x * c.x + a.y * c.y + a.z * c.z + a.w * c.w;
      }
      for (int off = 32; off; off >>= 1) acc += __shfl_xor(acc, off);
      val = acc + smv[bs] + emv[(b << 11) + t];
    }
    if (l == 0) band[(long)bs * 32 + j] = val;
  }
}

// ---------------- exact top-k (radix select + bitonic), one block per batch ----------------
__device__ __forceinline__ void bitonic1024(unsigned* buf) {
  int tid = threadIdx.x;
  __syncthreads();
  for (int k = 2; k <= 1024; k <<= 1)
    for (int j = k >> 1; j > 0; j >>= 1) {
      int ixj = tid ^ j;
      if (ixj > tid) {
        unsigned a = buf[tid], c = buf[ixj];
        bool up = ((tid & k) == 0);
        if (up ? (a > c) : (a < c)) { buf[tid] = c; buf[ixj] = a; }
      }
      __syncthreads();
    }
}

__global__ __launch_bounds__(1024) void k_topk(const float* __restrict__ band,
                                               const int* __restrict__ masks,
                                               int* __restrict__ starts, int* __restrict__ ends,
                                               float* __restrict__ tk, int* __restrict__ kvalid_out) {
  int b = blockIdx.x;
  const float* bb = band + (long)b * 65536;
  __shared__ unsigned hist[256];
  __shared__ int sh_digit, sh_R, sh_msum;
  __shared__ unsigned cntG, cntE;
  __shared__ unsigned listG[832];
  __shared__ unsigned listE[1024];
  __shared__ unsigned buf[1024];
  int tid = threadIdx.x;

  if (tid == 0) sh_msum = 0;
  __syncthreads();
  int pm = masks[b * S_ + tid] + masks[b * S_ + 1024 + tid];
  atomicAdd(&sh_msum, pm);
  __syncthreads();
  int kv = (int)((float)sh_msum * 0.4f);
  if (kv > MAXK) kv = MAXK;

  unsigned prefix = 0;
  int R = kv;
  if (kv > 0) {
    for (int shift = 24; shift >= 0; shift -= 8) {
      if (tid < 256) hist[tid] = 0;
      __syncthreads();
      for (int i = tid; i < 65536; i += 1024) {
        unsigned u = __float_as_uint(bb[i]);
        unsigned key = (u & 0x80000000u) ? ~u : (u | 0x80000000u);
        bool ok = (shift == 24) || ((key >> (shift + 8)) == (prefix >> (shift + 8)));
        if (ok) atomicAdd(&hist[(key >> shift) & 255u], 1u);
      }
      __syncthreads();
      if (tid == 0) {
        unsigned cum = 0; int d;
        for (d = 255; d >= 0; --d) {
          unsigned hc = hist[d];
          if (cum + hc >= (unsigned)R) break;
          cum += hc;
        }
        if (d < 0) d = 0;
        sh_digit = d; sh_R = R - (int)cum;
      }
      __syncthreads();
      prefix |= ((unsigned)sh_digit) << shift;
      R = sh_R;
      __syncthreads();
    }
  }
  if (tid == 0) { cntG = 0; cntE = 0; }
  __syncthreads();
  if (kv > 0) {
    for (int i = tid; i < 65536; i += 1024) {
      unsigned u = __float_as_uint(bb[i]);
      unsigned key = (u & 0x80000000u) ? ~u : (u | 0x80000000u);
      if (key > prefix) { unsigned p = atomicAdd(&cntG, 1u); if (p < 832) listG[p] = (unsigned)i; }
      else if (key == prefix) { unsigned p = atomicAdd(&cntE, 1u); if (p < 1024) listE[p] = (unsigned)i; }
    }
  }
  __syncthreads();
  int nG = (int)cntG, nE = (int)cntE, need = R;
  // sort ties ascending by item index (== flat index order), take smallest 'need'
  buf[tid] = (tid < nE) ? listE[tid] : 0xFFFFFFFFu;
  bitonic1024(buf);
  if (tid < need) listG[nG + tid] = buf[tid];
  __syncthreads();
  unsigned v2 = (tid < (unsigned)kv) ? listG[tid] : 0xFFFFFFFFu;
  __syncthreads();
  buf[tid] = v2;
  bitonic1024(buf);
  if (tid < MAXK) {
    int s, t; float val;
    if (tid < kv) {
      unsigned i = buf[tid];
      s = (int)(i >> 5); int j = (int)(i & 31); t = s + j;
      val = bb[i];
    } else {
      s = S_ - 1; t = S_ - 1;
      val = bb[(S_ - 1) * 32 + 0];
    }
    starts[b * KP_ + tid] = s;
    ends[b * KP_ + tid] = t;
    tk[b * KP_ + tid] = val;
  }
  if (tid == 0) kvalid_out[b] = kv;
}

// ---------------- gather span reps to bf16 (padded rows zero) ----------------
__global__ __launch_bounds__(256) void k_gather(const float* __restrict__ emb,
                                                const int* __restrict__ starts,
                                                const int* __restrict__ ends,
                                                __hip_bfloat16* __restrict__ reps_s,
                                                __hip_bfloat16* __restrict__ reps_e) {
  int r = blockIdx.x;                 // b*KP + k
  int b = r / KP_, k = r % KP_;
  long ob = (long)r * 1024;
  if (k >= MAXK) {
    __hip_bfloat16 z = __float2bfloat16(0.0f);
    for (int c = threadIdx.x; c < 1024; c += 256) { reps_s[ob + c] = z; reps_e[ob + c] = z; }
    return;
  }
  const float* ps = emb + ((long)b * S_ + starts[r]) * 1024;
  const float* pe = emb + ((long)b * S_ + ends[r]) * 1024;
  for (int c = threadIdx.x; c < 1024; c += 256) {
    reps_s[ob + c] = __float2bfloat16(ps[c]);
    reps_e[ob + c] = __float2bfloat16(pe[c]);
  }
}

// ---------------- antecedent bias vector ----------------
__global__ __launch_bounds__(256) void k_bias(const __hip_bfloat16* __restrict__ a_s,
                                              const __hip_bfloat16* __restrict__ a_e,
                                              const float* __restrict__ Bs2s, const float* __restrict__ Be2e,
                                              const float* __restrict__ Bs2e, const float* __restrict__ Be2s,
                                              float* __restrict__ biasv) {
  int w = threadIdx.x >> 6, l = threadIdx.x & 63;
  int row = blockIdx.x * 4 + w;       // z*KP + lidx
  if (row >= Z_ * KP_) return;
  int z = row / KP_, n = z % NC_;
  const __hip_bfloat16* as = a_s + (long)row * FF_;
  const __hip_bfloat16* ae = a_e + (long)row * FF_;
  const float* b1a = Bs2s + n * FF_;
  const float* b1b = Be2s + n * FF_;
  const float* b2a = Be2e + n * FF_;
  const float* b2b = Bs2e + n * FF_;
  float acc = 0.f;
  for (int q = 0; q < 16; ++q) {
    int c = l + 64 * q;
    acc += __bfloat162float(as[c]) * (b1a[c] + b1b[c]);
    acc += __bfloat162float(ae[c]) * (b2a[c] + b2b[c]);
  }
  for (int off = 32; off; off >>= 1) acc += __shfl_xor(acc, off);
  if (l == 0) biasv[row] = acc;
}

// ---------------- output epilogue: + bias[l] + mask + pair ----------------
__global__ __launch_bounds__(256) void k_epi(float* __restrict__ outp,
                                             const float* __restrict__ biasv,
                                             const float* __restrict__ tk,
                                             const int* __restrict__ kvalid) {
  int idx = blockIdx.x * 256 + threadIdx.x;
  const int TOT = Z_ * MAXK * MAXK;
  if (idx >= TOT) return;
  int z = idx / (MAXK * MAXK);
  int rem = idx - z * (MAXK * MAXK);
  int k = rem / MAXK, l = rem - k * MAXK;
  int b = z / NC_;
  float v = outp[idx] + biasv[z * KP_ + l] + tk[b * KP_ + k] + tk[b * KP_ + l];
  if (!(l < k && l < kvalid[b])) v += NEGV;
  outp[idx] = v;
}

// =====================================================================
extern "C" void kernel_launch(void* const* d_in, const int* in_sizes, int n_in,
                              void* d_out, int out_size, void* d_ws, size_t ws_size,
                              hipStream_t stream) {
  const float* x_emb = (const float*)d_in[0];
  const int*   masks = (const int*)d_in[1];
  const float* smW  = (const float*)d_in[2];
  const float* smb  = (const float*)d_in[3];
  const float* smg  = (const float*)d_in[4];
  const float* smbe = (const float*)d_in[5];
  const float* emW  = (const float*)d_in[6];
  const float* embb = (const float*)d_in[7];
  const float* emg  = (const float*)d_in[8];
  const float* embe = (const float*)d_in[9];
  const float* msw  = (const float*)d_in[10];
  const float* msb  = (const float*)d_in[11];
  const float* mew  = (const float*)d_in[12];
  const float* meb  = (const float*)d_in[13];
  const float* s2eW = (const float*)d_in[14];
  const float* s2eb = (const float*)d_in[15];
  const float* csW  = (const float*)d_in[16];
  const float* csb  = (const float*)d_in[17];
  const float* csg  = (const float*)d_in[18];
  const float* csbe = (const float*)d_in[19];
  const float* ceW  = (const float*)d_in[20];
  const float* ceb  = (const float*)d_in[21];
  const float* ceg  = (const float*)d_in[22];
  const float* cebe = (const float*)d_in[23];
  const float* Ws2s = (const float*)d_in[24];
  const float* We2e = (const float*)d_in[25];
  const float* Ws2e = (const float*)d_in[26];
  const float* We2s = (const float*)d_in[27];
  const float* Bs2s = (const float*)d_in[28];
  const float* Be2e = (const float*)d_in[29];
  const float* Bs2e = (const float*)d_in[30];
  const float* Be2s = (const float*)d_in[31];
  float* outp = (float*)d_out;
  char* ws = (char*)d_ws;
  (void)in_sizes; (void)n_in; (void)out_size; (void)ws_size;

  size_t o = 0;
  auto alloc = [&](size_t bytes) { size_t r = o; o += (bytes + 255) & ~(size_t)255; return r; };
  // region A (dead after stage-A/C GEMMs)
  size_t o_embh = alloc(8388608), o_embl = alloc(8388608);
  size_t o_smWh = alloc(2097152), o_smWl = alloc(2097152);
  size_t o_emWh = alloc(2097152), o_emWl = alloc(2097152);
  size_t o_s2eWh = alloc(2097152), o_s2eWl = alloc(2097152);
  // region B (dead after band/topk)
  size_t o_s = alloc(16777216), o_e = alloc(16777216), o_s2 = alloc(16777216);
  size_t o_sh = alloc(8388608), o_sl = alloc(8388608);
  (void)o_sh; (void)o_sl;
  // persistent
  size_t o_smv = alloc(16384), o_emv = alloc(16384);
  size_t o_band = alloc(524288);
  size_t o_starts = alloc(7168), o_ends = alloc(7168), o_tk = alloc(7168), o_kv = alloc(256);
  size_t o_repss = alloc(3670016), o_repse = alloc(3670016);
  size_t o_csWb = alloc(14680064), o_ceWb = alloc(14680064);
  size_t o_as = alloc(25690112), o_ae = alloc(25690112);
  size_t o_W0 = alloc(14680064), o_W1 = alloc(14680064), o_W2 = alloc(14680064), o_W3 = alloc(14680064);
  size_t o_biasv = alloc(65536);
  // aliases (liveness-checked): h over region B; V1/V2 over region A(+B head)
  size_t o_h  = o_s;
  size_t o_V1 = o_embh;
  size_t o_V2 = o_embh + 25690112;

  __hip_bfloat16* embh = (__hip_bfloat16*)(ws + o_embh);
  __hip_bfloat16* embl = (__hip_bfloat16*)(ws + o_embl);
  __hip_bfloat16* smWh = (__hip_bfloat16*)(ws + o_smWh);
  __hip_bfloat16* smWl = (__hip_bfloat16*)(ws + o_smWl);
  __hip_bfloat16* emWh = (__hip_bfloat16*)(ws + o_emWh);
  __hip_bfloat16* emWl = (__hip_bfloat16*)(ws + o_emWl);
  __hip_bfloat16* s2eWh = (__hip_bfloat16*)(ws + o_s2eWh);
  __hip_bfloat16* s2eWl = (__hip_bfloat16*)(ws + o_s2eWl);
  float* s_buf  = (float*)(ws + o_s);
  float* e_buf  = (float*)(ws + o_e);
  float* s2_buf = (float*)(ws + o_s2);
  __hip_bfloat16* sh_p = (__hip_bfloat16*)(ws + o_sh);
  __hip_bfloat16* sl_p = (__hip_bfloat16*)(ws + o_sl);
  float* smv_p = (float*)(ws + o_smv);
  float* emv_p = (float*)(ws + o_emv);
  float* band_p = (float*)(ws + o_band);
  int* starts_p = (int*)(ws + o_starts);
  int* ends_p = (int*)(ws + o_ends);
  float* tk_p = (float*)(ws + o_tk);
  int* kv_p = (int*)(ws + o_kv);
  __hip_bfloat16* repss_p = (__hip_bfloat16*)(ws + o_repss);
  __hip_bfloat16* repse_p = (__hip_bfloat16*)(ws + o_repse);
  __hip_bfloat16* csWb_p = (__hip_bfloat16*)(ws + o_csWb);
  __hip_bfloat16* ceWb_p = (__hip_bfloat16*)(ws + o_ceWb);
  __hip_bfloat16* as_p = (__hip_bfloat16*)(ws + o_as);
  __hip_bfloat16* ae_p = (__hip_bfloat16*)(ws + o_ae);
  __hip_bfloat16* W0_p = (__hip_bfloat16*)(ws + o_W0);
  __hip_bfloat16* W1_p = (__hip_bfloat16*)(ws + o_W1);
  __hip_bfloat16* W2_p = (__hip_bfloat16*)(ws + o_W2);
  __hip_bfloat16* W3_p = (__hip_bfloat16*)(ws + o_W3);
  float* h_buf = (float*)(ws + o_h);
  __hip_bfloat16* V1_p = (__hip_bfloat16*)(ws + o_V1);
  __hip_bfloat16* V2_p = (__hip_bfloat16*)(ws + o_V2);
  float* biasv_p = (float*)(ws + o_biasv);

  // ---- stage A: s = fc(emb, smW), e = fc(emb, emW) [split-bf16 ~f32 accuracy] ----
  k_split<<<4096, 256, 0, stream>>>(x_emb, embh, embl, 4194304);
  k_split<<<4096, 256, 0, stream>>>(smW, smWh, smWl, 1048576);
  k_split<<<4096, 256, 0, stream>>>(emW, emWh, emWl, 1048576);
  k_split<<<4096, 256, 0, stream>>>(s2eW, s2eWh, s2eWl, 1048576);

  k_gemm<2, false><<<dim3(32, 8, 1), 256, 0, stream>>>(embh, embl, smWh, smWl,
      s_buf, smb, 1024, 0, 0, 0, 0, 1024, 4096, 1024);
  k_gelu_ln<4><<<4096, 256, 0, stream>>>(s_buf, smg, smbe);
  k_gemm<2, false><<<dim3(32, 8, 1), 256, 0, stream>>>(embh, embl, emWh, emWl,
      e_buf, embb, 1024, 0, 0, 0, 0, 1024, 4096, 1024);
  k_gelu_ln<4><<<4096, 256, 0, stream>>>(e_buf, emg, embe);

  // ---- stage C: s2 = s@s2e_W^T + b; banded scores ----
  k_split<<<4096, 256, 0, stream>>>(s_buf, sh_p, sl_p, 4194304);
  k_gemm<2, false><<<dim3(32, 8, 1), 256, 0, stream>>>(sh_p, sl_p, s2eWh, s2eWl,
      s2_buf, s2eb, 1024, 0, 0, 0, 0, 1024, 4096, 1024);
  k_rowdot<<<1024, 256, 0, stream>>>(s_buf, msw, msb, smv_p, 4096);
  k_rowdot<<<1024, 256, 0, stream>>>(e_buf, mew, meb, emv_p, 4096);
  k_band<<<4096, 256, 0, stream>>>(s2_buf, e_buf, smv_p, emv_p, band_p);

  // ---- stage D: exact top-k ----
  k_topk<<<2, 1024, 0, stream>>>(band_p, masks, starts_p, ends_p, tk_p, kv_p);

  // ---- stage E/F: gather + fc to per-category reps ----
  k_gather<<<2 * KP_, 256, 0, stream>>>(x_emb, starts_p, ends_p, repss_p, repse_p);
  k_cast<<<4096, 256, 0, stream>>>(csW, csWb_p, 7340032);
  k_cast<<<4096, 256, 0, stream>>>(ceW, ceWb_p, 7340032);
  k_gemm<0, false><<<dim3(14, 56, 1), 256, 0, stream>>>(repss_p, nullptr, csWb_p, nullptr,
      h_buf, csb, 1024, 0, 0, 0, 0, NF_, 2 * KP_, NF_);
  k_gelu_ln_cats<<<2 * KP_, 256, 0, stream>>>(h_buf, csg, csbe, as_p);
  k_gemm<0, false><<<dim3(14, 56, 1), 256, 0, stream>>>(repse_p, nullptr, ceWb_p, nullptr,
      h_buf, ceb, 1024, 0, 0, 0, 0, NF_, 2 * KP_, NF_);
  k_gelu_ln_cats<<<2 * KP_, 256, 0, stream>>>(h_buf, ceg, cebe, ae_p);

  // ---- stage G: bilinear via V1/V2 then logits ----
  k_cast<<<4096, 256, 0, stream>>>(Ws2s, W0_p, 7340032);
  k_cast<<<4096, 256, 0, stream>>>(We2e, W1_p, 7340032);
  k_cast<<<4096, 256, 0, stream>>>(Ws2e, W2_p, 7340032);
  k_cast<<<4096, 256, 0, stream>>>(We2s, W3_p, 7340032);
  // V1 = a_s@Ws2s^T + a_e@Ws2e^T ; V2 = a_e@We2e^T + a_s@We2s^T   (per z=b*7+n)
  k_gemm<1, true><<<dim3(7, 8, 14), 256, 0, stream>>>(as_p, ae_p, W0_p, W2_p,
      V1_p, nullptr, 1024, 917504, 1048576, 1, 917504, 1024, KP_, 1024);
  k_gemm<1, true><<<dim3(7, 8, 14), 256, 0, stream>>>(ae_p, as_p, W1_p, W3_p,
      V2_p, nullptr, 1024, 917504, 1048576, 1, 917504, 1024, KP_, 1024);
  k_bias<<<(Z_ * KP_) / 4, 256, 0, stream>>>(as_p, ae_p, Bs2s, Be2e, Bs2e, Be2s, biasv_p);
  // logits[k,l] = a_s[k].V1[l] + a_e[k].V2[l]  -> straight into d_out
  k_gemm<1, false><<<dim3(7, 7, 14), 256, 0, stream>>>(as_p, ae_p, V1_p, V2_p,
      outp, nullptr, 1024, 917504, 917504, 0, (long)MAXK * MAXK, MAXK, MAXK, MAXK);
  // ---- epilogue: + bias[l] + pair + mask ----
  k_epi<<<(Z_ * MAXK * MAXK + 255) / 256, 256, 0, stream>>>(outp, biasv_p, tk_p, kv_p);
}

// Round 2
// 917.962 us; speedup vs baseline: 1.3681x; 1.3681x over previous
//
#include <hip/hip_runtime.h>
#include <hip/hip_bf16.h>
#include <math.h>

// ---- problem constants ----
#define S_    2048
#define NC_   7
#define MAXK  819
#define NK    1024          // padded top-k rows (4*256)
#define Z_    14            // B*NUM_CATS
#define NEGV  (-10000.0f)

typedef __attribute__((ext_vector_type(8))) short bf16x8;
typedef __attribute__((ext_vector_type(4))) float f32x4;

__device__ __forceinline__ void gload_lds16(const void* g, void* l) {
  __builtin_amdgcn_global_load_lds((const __attribute__((address_space(1))) unsigned int*)g,
                                   (__attribute__((address_space(3))) unsigned int*)l, 16, 0, 0);
}

__device__ __forceinline__ float gelu_exact(float x) {
  return 0.5f * x * (1.0f + erff(x * 0.70710678118654752f));
}
__device__ __forceinline__ unsigned short f2bf(float x) {
  __hip_bfloat16 h = __float2bfloat16(x);
  return *(unsigned short*)&h;
}
__device__ __forceinline__ float bf2f(unsigned short u) {
  __hip_bfloat16 h; *(unsigned short*)&h = u;
  return __bfloat162float(h);
}

// ============ 256x256 8-wave GEMM, BK=64, counted-vmcnt pipeline ============
// C[m,n] = sum_k A[m,k]*B[n,k]  (both row-major with K inner)
// M,N multiples of 256; K multiple of 64.
template<bool OBF16, bool BIAS2>
__global__ __launch_bounds__(512, 2) void k_gemm8(
    const __hip_bfloat16* __restrict__ A, const __hip_bfloat16* __restrict__ B,
    void* __restrict__ Cv, const float* __restrict__ bias1, const float* __restrict__ bias2,
    int K, int nbn, long strideA, long strideB, int bmod7, long strideC,
    int ldc, int Mstore, int Nstore)
{
  __shared__ __align__(16) __hip_bfloat16 lds[2][2][256 * 64];   // 128 KiB
  const int tid = threadIdx.x;
  const int z = blockIdx.z;
  // bijective XCD swizzle (m204)
  const int nwg = gridDim.x;
  const int xcd = blockIdx.x & 7, loc = blockIdx.x >> 3;
  const int q = nwg >> 3, r = nwg & 7;
  const int wg = (xcd < r ? xcd * (q + 1) : r * (q + 1) + (xcd - r) * q) + loc;
  const int bm = wg / nbn, bn = wg % nbn;
  const int m0 = bm * 256, n0 = bn * 256;
  const __hip_bfloat16* pA = A + (long)z * strideA;
  const __hip_bfloat16* pB = B + (long)(bmod7 ? (z % 7) : z) * strideB;
  const int wave = tid >> 6, lane = tid & 63;
  const int wm = wave >> 2, wn = wave & 3;
  const int lr = lane & 15, kh = lane >> 4;

  f32x4 acc[8][4];
  #pragma unroll
  for (int i = 0; i < 8; ++i)
    #pragma unroll
    for (int j = 0; j < 4; ++j)
      #pragma unroll
      for (int rr = 0; rr < 4; ++rr) acc[i][j][rr] = 0.0f;

  const long Kb = (long)K * 2;   // row stride bytes

  auto stage = [&](int kt, int bb) {
    const long kbyte = (long)kt * 128;
    #pragma unroll
    for (int j = 0; j < 4; ++j) {
      int off = j * 8192 + tid * 16;
      int row = off >> 7, c = off & 127;
      int gc = c ^ ((row & 7) << 4);          // inverse swizzle on global source
      gload_lds16((const char*)pA + (long)(m0 + row) * Kb + kbyte + gc,
                  (char*)&lds[bb][0][0] + off);
      gload_lds16((const char*)pB + (long)(n0 + row) * Kb + kbyte + gc,
                  (char*)&lds[bb][1][0] + off);
    }
  };

  auto compute = [&](int bb) {
    const char* la = (const char*)&lds[bb][0][0];
    const char* lb = (const char*)&lds[bb][1][0];
    #pragma unroll
    for (int kk = 0; kk < 2; ++kk) {
      const int kbase = kk * 64 + kh * 16;
      bf16x8 af[8], bfr[4];
      #pragma unroll
      for (int mi = 0; mi < 8; ++mi) {
        int row = wm * 128 + mi * 16 + lr;
        af[mi] = *(const bf16x8*)(la + row * 128 + (kbase ^ ((row & 7) << 4)));
      }
      #pragma unroll
      for (int ni = 0; ni < 4; ++ni) {
        int row = wn * 64 + ni * 16 + lr;
        bfr[ni] = *(const bf16x8*)(lb + row * 128 + (kbase ^ ((row & 7) << 4)));
      }
      __builtin_amdgcn_s_setprio(1);
      #pragma unroll
      for (int mi = 0; mi < 8; ++mi)
        #pragma unroll
        for (int ni = 0; ni < 4; ++ni)
          acc[mi][ni] = __builtin_amdgcn_mfma_f32_16x16x32_bf16(af[mi], bfr[ni], acc[mi][ni], 0, 0, 0);
      __builtin_amdgcn_s_setprio(0);
    }
  };

  const int nt = K >> 6;
  stage(0, 0);
  int cur = 0;
  for (int t = 0; t < nt - 1; ++t) {
    stage(t + 1, cur ^ 1);                       // prefetch next tile
    asm volatile("s_waitcnt vmcnt(8)" ::: "memory");   // current tile landed
    asm volatile("" ::: "memory");
    __builtin_amdgcn_s_barrier();
    asm volatile("" ::: "memory");
    compute(cur);
    asm volatile("" ::: "memory");
    __builtin_amdgcn_s_barrier();
    asm volatile("" ::: "memory");
    cur ^= 1;
  }
  asm volatile("s_waitcnt vmcnt(0)" ::: "memory");
  asm volatile("" ::: "memory");
  __builtin_amdgcn_s_barrier();
  asm volatile("" ::: "memory");
  compute(cur);

  const long coff = (long)z * strideC;
  #pragma unroll
  for (int mi = 0; mi < 8; ++mi) {
    #pragma unroll
    for (int ni = 0; ni < 4; ++ni) {
      int n = n0 + wn * 64 + ni * 16 + lr;
      if (n >= Nstore) continue;
      float badd = 0.f;
      if (bias1) badd = (BIAS2 && n >= 1024) ? bias2[n - 1024] : bias1[n];
      #pragma unroll
      for (int rr = 0; rr < 4; ++rr) {
        int m = m0 + wm * 128 + mi * 16 + kh * 4 + rr;
        if (m >= Mstore) continue;
        float v = acc[mi][ni][rr] + badd;
        if (OBF16) ((__hip_bfloat16*)Cv)[coff + (long)m * ldc + n] = __float2bfloat16(v);
        else       ((float*)Cv)[coff + (long)m * ldc + n] = v;
      }
    }
  }
}

// ---------- pack split3: dst rows 3072 wide. APAT: [hi|hi|lo]; else [hi|lo|hi] ----------
template<bool APAT>
__global__ __launch_bounds__(256) void k_packsplit3(const float* __restrict__ s1, long stride1,
                                                    const float* __restrict__ s2, int split,
                                                    __hip_bfloat16* __restrict__ dst) {
  long idx4 = ((long)blockIdx.x * 256 + threadIdx.x) * 4;
  int rrow = (int)(idx4 >> 10), c = (int)(idx4 & 1023);
  const float* src = (rrow < split) ? s1 + (long)rrow * stride1 + c
                                    : s2 + (long)(rrow - split) * 1024 + c;
  float4 v = *(const float4*)src;
  float f[4] = {v.x, v.y, v.z, v.w};
  unsigned short h[4], l4[4];
  #pragma unroll
  for (int i = 0; i < 4; ++i) {
    h[i] = f2bf(f[i]);
    l4[i] = f2bf(f[i] - bf2f(h[i]));
  }
  unsigned short* d = (unsigned short*)dst + (long)rrow * 3072;
  ushort4 hv = {h[0], h[1], h[2], h[3]};
  ushort4 lv = {l4[0], l4[1], l4[2], l4[3]};
  *(ushort4*)(d + c)                         = hv;
  *(ushort4*)(d + 1024 + c)                  = APAT ? hv : lv;
  *(ushort4*)(d + 2048 + c)                  = APAT ? lv : hv;
}

// ---------- f32 -> bf16 vector cast ----------
__global__ __launch_bounds__(256) void k_cast4(const float* __restrict__ x,
                                               __hip_bfloat16* __restrict__ y, long n4) {
  long i = (long)blockIdx.x * 256 + threadIdx.x;
  if (i >= n4) return;
  float4 v = ((const float4*)x)[i];
  ushort4 o = {f2bf(v.x), f2bf(v.y), f2bf(v.z), f2bf(v.w)};
  ((ushort4*)y)[i] = o;
}

// ---------- pack Bbig[cat][n(2048)][k(2048)] from 4 weight tensors ----------
__global__ __launch_bounds__(256) void k_packBbig(const float* __restrict__ Ws2s,
                                                  const float* __restrict__ We2e,
                                                  const float* __restrict__ Ws2e,
                                                  const float* __restrict__ We2s,
                                                  __hip_bfloat16* __restrict__ dst) {
  long idx4 = ((long)blockIdx.x * 256 + threadIdx.x) * 4;
  long rowid = idx4 >> 11;
  int c = (int)(idx4 & 2047);
  int cat = (int)(rowid >> 11);
  int n = (int)(rowid & 2047);
  const float* src;
  if (n < 1024) src = (c < 1024) ? Ws2s + ((long)cat * 1024 + n) * 1024 + c
                                 : Ws2e + ((long)cat * 1024 + n) * 1024 + (c - 1024);
  else          src = (c < 1024) ? We2s + ((long)cat * 1024 + (n - 1024)) * 1024 + c
                                 : We2e + ((long)cat * 1024 + (n - 1024)) * 1024 + (c - 1024);
  float4 v = *(const float4*)src;
  ushort4 o = {f2bf(v.x), f2bf(v.y), f2bf(v.z), f2bf(v.w)};
  *(ushort4*)((unsigned short*)dst + idx4) = o;
}

// ---------- GELU + LayerNorm over 1024 cols, in-place, strided rows ----------
__global__ __launch_bounds__(256) void k_gelu_ln(float* __restrict__ h, long rowstride, int coff,
                                                 const float* __restrict__ g,
                                                 const float* __restrict__ beta) {
  long base = (long)blockIdx.x * rowstride + coff;
  float v[4];
  float s = 0.f, s2 = 0.f;
  #pragma unroll
  for (int i = 0; i < 4; ++i) {
    float x = h[base + i * 256 + threadIdx.x];
    float ge = gelu_exact(x);
    v[i] = ge; s += ge; s2 += ge * ge;
  }
  __shared__ float red0[4], red1[4];
  for (int off = 32; off; off >>= 1) { s += __shfl_xor(s, off); s2 += __shfl_xor(s2, off); }
  int w = threadIdx.x >> 6;
  if ((threadIdx.x & 63) == 0) { red0[w] = s; red1[w] = s2; }
  __syncthreads();
  s  = red0[0] + red0[1] + red0[2] + red0[3];
  s2 = red1[0] + red1[1] + red1[2] + red1[3];
  float mu  = s / 1024.0f;
  float var = s2 / 1024.0f - mu * mu;
  float inv = 1.0f / sqrtf(var + 1e-5f);
  #pragma unroll
  for (int i = 0; i < 4; ++i) {
    int c = i * 256 + threadIdx.x;
    h[base + c] = (v[i] - mu) * inv * g[c] + beta[c];
  }
}

// ---------- GELU+LN over 7168, write bf16 into a_cat[z][k][2048] half ----------
__global__ __launch_bounds__(256) void k_gelu_ln_cats(const float* __restrict__ h,
                                                      const float* __restrict__ g,
                                                      const float* __restrict__ beta,
                                                      __hip_bfloat16* __restrict__ a_cat, int half) {
  const int VPT = 28;
  int r = blockIdx.x;                       // 0..2047
  int b = r >> 10, k = r & 1023;
  const float* row = h + (long)r * 7168;
  float v[VPT];
  float s = 0.f, s2 = 0.f;
  #pragma unroll
  for (int i = 0; i < VPT; ++i) {
    float x = row[i * 256 + threadIdx.x];
    float ge = gelu_exact(x);
    v[i] = ge; s += ge; s2 += ge * ge;
  }
  __shared__ float red0[4], red1[4];
  for (int off = 32; off; off >>= 1) { s += __shfl_xor(s, off); s2 += __shfl_xor(s2, off); }
  int w = threadIdx.x >> 6;
  if ((threadIdx.x & 63) == 0) { red0[w] = s; red1[w] = s2; }
  __syncthreads();
  s  = red0[0] + red0[1] + red0[2] + red0[3];
  s2 = red1[0] + red1[1] + red1[2] + red1[3];
  float mu  = s / 7168.0f;
  float var = s2 / 7168.0f - mu * mu;
  float inv = 1.0f / sqrtf(var + 1e-5f);
  #pragma unroll
  for (int i = 0; i < VPT; ++i) {
    int c = i * 256 + threadIdx.x;
    int n = c >> 10, f = c & 1023;
    float val = (v[i] - mu) * inv * g[c] + beta[c];
    a_cat[((long)((b * NC_ + n) * NK + k)) * 2048 + half * 1024 + f] = __float2bfloat16(val);
  }
}

// ---------- row dot: out[r] = X[r,:1024].w + b0 ----------
__global__ __launch_bounds__(256) void k_rowdot(const float* __restrict__ X, long rowstride, int coff,
                                                const float* __restrict__ wv,
                                                const float* __restrict__ b0,
                                                float* __restrict__ outp, int rows) {
  int w = threadIdx.x >> 6, l = threadIdx.x & 63;
  int row = blockIdx.x * 4 + w;
  if (row >= rows) return;
  const float4* xp = (const float4*)(X + (long)row * rowstride + coff);
  const float4* wp = (const float4*)wv;
  float acc = 0.f;
  #pragma unroll
  for (int qq = 0; qq < 4; ++qq) {
    float4 a = xp[l + 64 * qq], b = wp[l + 64 * qq];
    acc += a.x * b.x + a.y * b.y + a.z * b.z + a.w * b.w;
  }
  for (int off = 32; off; off >>= 1) acc += __shfl_xor(acc, off);
  if (l == 0) outp[row] = acc + b0[0];
}

// ---------- banded scores ----------
__global__ __launch_bounds__(256) void k_band(const float* __restrict__ s2m,
                                              const float* __restrict__ se,
                                              const float* __restrict__ smv,
                                              const float* __restrict__ emv,
                                              float* __restrict__ band) {
  __shared__ float s2row[1024];
  int bs = blockIdx.x;                 // b*2048+s
  const float* sp = s2m + (long)bs * 1024;
  for (int i = threadIdx.x; i < 1024; i += 256) s2row[i] = sp[i];
  __syncthreads();
  int b = bs >> 11, s = bs & 2047;
  int w = threadIdx.x >> 6, l = threadIdx.x & 63;
  for (int j = w; j < 32; j += 4) {
    int t = s + j;
    float val = -3.0e38f;
    if (j < 30 && t < S_) {
      const float4* ep = (const float4*)(se + ((long)((b << 11) + t)) * 2048 + 1024);
      const float4* zp = (const float4*)s2row;
      float acc = 0.f;
      #pragma unroll
      for (int qq = 0; qq < 4; ++qq) {
        float4 a = ep[l + 64 * qq], c = zp[l + 64 * qq];
        acc += a.x * c.x + a.y * c.y + a.z * c.z + a.w * c.w;
      }
      for (int off = 32; off; off >>= 1) acc += __shfl_xor(acc, off);
      val = acc + smv[bs] + emv[(b << 11) + t];
    }
    if (l == 0) band[(long)bs * 32 + j] = val;
  }
}

// ---------- exact top-k (radix select + bitonic), one block per batch ----------
__device__ __forceinline__ void bitonic1024(unsigned* buf) {
  int tid = threadIdx.x;
  __syncthreads();
  for (int k = 2; k <= 1024; k <<= 1)
    for (int j = k >> 1; j > 0; j >>= 1) {
      int ixj = tid ^ j;
      if (ixj > tid) {
        unsigned a = buf[tid], c = buf[ixj];
        bool up = ((tid & k) == 0);
        if (up ? (a > c) : (a < c)) { buf[tid] = c; buf[ixj] = a; }
      }
      __syncthreads();
    }
}

__global__ __launch_bounds__(1024) void k_topk(const float* __restrict__ band,
                                               const int* __restrict__ masks,
                                               int* __restrict__ starts, int* __restrict__ ends,
                                               float* __restrict__ tk, int* __restrict__ kvalid_out) {
  int b = blockIdx.x;
  const float* bb = band + (long)b * 65536;
  __shared__ unsigned hist[256];
  __shared__ int sh_digit, sh_R, sh_msum;
  __shared__ unsigned cntG, cntE;
  __shared__ unsigned listG[832];
  __shared__ unsigned listE[1024];
  __shared__ unsigned buf[1024];
  int tid = threadIdx.x;

  if (tid == 0) sh_msum = 0;
  __syncthreads();
  int pm = masks[b * S_ + tid] + masks[b * S_ + 1024 + tid];
  atomicAdd(&sh_msum, pm);
  __syncthreads();
  int kv = (int)((float)sh_msum * 0.4f);
  if (kv > MAXK) kv = MAXK;

  unsigned prefix = 0;
  int R = kv;
  if (kv > 0) {
    for (int shift = 24; shift >= 0; shift -= 8) {
      if (tid < 256) hist[tid] = 0;
      __syncthreads();
      for (int i = tid; i < 65536; i += 1024) {
        unsigned u = __float_as_uint(bb[i]);
        unsigned key = (u & 0x80000000u) ? ~u : (u | 0x80000000u);
        bool ok = (shift == 24) || ((key >> (shift + 8)) == (prefix >> (shift + 8)));
        if (ok) atomicAdd(&hist[(key >> shift) & 255u], 1u);
      }
      __syncthreads();
      if (tid == 0) {
        unsigned cum = 0; int d;
        for (d = 255; d >= 0; --d) {
          unsigned hc = hist[d];
          if (cum + hc >= (unsigned)R) break;
          cum += hc;
        }
        if (d < 0) d = 0;
        sh_digit = d; sh_R = R - (int)cum;
      }
      __syncthreads();
      prefix |= ((unsigned)sh_digit) << shift;
      R = sh_R;
      __syncthreads();
    }
  }
  if (tid == 0) { cntG = 0; cntE = 0; }
  __syncthreads();
  if (kv > 0) {
    for (int i = tid; i < 65536; i += 1024) {
      unsigned u = __float_as_uint(bb[i]);
      unsigned key = (u & 0x80000000u) ? ~u : (u | 0x80000000u);
      if (key > prefix) { unsigned p = atomicAdd(&cntG, 1u); if (p < 832) listG[p] = (unsigned)i; }
      else if (key == prefix) { unsigned p = atomicAdd(&cntE, 1u); if (p < 1024) listE[p] = (unsigned)i; }
    }
  }
  __syncthreads();
  int nG = (int)cntG, nE = (int)cntE, need = R;
  buf[tid] = (tid < nE) ? listE[tid] : 0xFFFFFFFFu;
  bitonic1024(buf);
  if (tid < need) listG[nG + tid] = buf[tid];
  __syncthreads();
  unsigned v2 = (tid < (unsigned)kv) ? listG[tid] : 0xFFFFFFFFu;
  __syncthreads();
  buf[tid] = v2;
  bitonic1024(buf);
  {
    int s, t; float val;
    if (tid < kv) {
      unsigned i = buf[tid];
      s = (int)(i >> 5); t = s + (int)(i & 31);
      val = bb[i];
    } else {
      s = S_ - 1; t = S_ - 1;
      val = bb[(S_ - 1) * 32 + 0];
    }
    starts[b * NK + tid] = s;
    ends[b * NK + tid] = t;
    tk[b * NK + tid] = val;
  }
  if (tid == 0) kvalid_out[b] = kv;
}

// ---------- gather span reps to bf16 ----------
__global__ __launch_bounds__(256) void k_gather(const float* __restrict__ emb,
                                                const int* __restrict__ starts,
                                                const int* __restrict__ ends,
                                                __hip_bfloat16* __restrict__ reps_s,
                                                __hip_bfloat16* __restrict__ reps_e) {
  int r = blockIdx.x;                 // b*NK + k
  int b = r >> 10;
  long ob = (long)r * 1024;
  const float4* ps = (const float4*)(emb + ((long)b * S_ + starts[r]) * 1024);
  const float4* pe = (const float4*)(emb + ((long)b * S_ + ends[r]) * 1024);
  unsigned short* ds = (unsigned short*)reps_s + ob;
  unsigned short* de = (unsigned short*)reps_e + ob;
  int c4 = threadIdx.x;               // 256 threads * 4 elems
  float4 a = ps[c4], e = pe[c4];
  ushort4 oa = {f2bf(a.x), f2bf(a.y), f2bf(a.z), f2bf(a.w)};
  ushort4 oe = {f2bf(e.x), f2bf(e.y), f2bf(e.z), f2bf(e.w)};
  *(ushort4*)(ds + c4 * 4) = oa;
  *(ushort4*)(de + c4 * 4) = oe;
}

// ---------- antecedent bias vector (reads a_cat) ----------
__global__ __launch_bounds__(256) void k_bias(const __hip_bfloat16* __restrict__ a_cat,
                                              const float* __restrict__ Bs2s, const float* __restrict__ Be2e,
                                              const float* __restrict__ Bs2e, const float* __restrict__ Be2s,
                                              float* __restrict__ biasv) {
  int w = threadIdx.x >> 6, l = threadIdx.x & 63;
  int row = blockIdx.x * 4 + w;       // z*NK + lidx
  if (row >= Z_ * NK) return;
  int z = row >> 10, cat = z % NC_;
  const unsigned short* ar = (const unsigned short*)a_cat + (long)row * 2048;
  const float* b1 = Bs2s + cat * 1024;
  const float* b2 = Be2s + cat * 1024;
  const float* b3 = Be2e + cat * 1024;
  const float* b4 = Bs2e + cat * 1024;
  float acc = 0.f;
  for (int qq = 0; qq < 16; ++qq) {
    int c = l + 64 * qq;
    acc += bf2f(ar[c]) * (b1[c] + b2[c]);
    acc += bf2f(ar[1024 + c]) * (b3[c] + b4[c]);
  }
  for (int off = 32; off; off >>= 1) acc += __shfl_xor(acc, off);
  if (l == 0) biasv[row] = acc;
}

// ---------- output epilogue ----------
__global__ __launch_bounds__(256) void k_epi(float* __restrict__ outp,
                                             const float* __restrict__ biasv,
                                             const float* __restrict__ tk,
                                             const int* __restrict__ kvalid) {
  long idx = (long)blockIdx.x * 256 + threadIdx.x;
  const long TOT = (long)Z_ * MAXK * MAXK;
  if (idx >= TOT) return;
  int z = (int)(idx / (MAXK * MAXK));
  int rem = (int)(idx - (long)z * (MAXK * MAXK));
  int k = rem / MAXK, l = rem - k * MAXK;
  int b = z / NC_;
  float v = outp[idx] + biasv[z * NK + l] + tk[b * NK + k] + tk[b * NK + l];
  if (!(l < k && l < kvalid[b])) v += NEGV;
  outp[idx] = v;
}

// =====================================================================
extern "C" void kernel_launch(void* const* d_in, const int* in_sizes, int n_in,
                              void* d_out, int out_size, void* d_ws, size_t ws_size,
                              hipStream_t stream) {
  const float* x_emb = (const float*)d_in[0];
  const int*   masks = (const int*)d_in[1];
  const float* smW  = (const float*)d_in[2];
  const float* smb  = (const float*)d_in[3];
  const float* smg  = (const float*)d_in[4];
  const float* smbe = (const float*)d_in[5];
  const float* emW  = (const float*)d_in[6];
  const float* embb = (const float*)d_in[7];
  const float* emg  = (const float*)d_in[8];
  const float* embe = (const float*)d_in[9];
  const float* msw  = (const float*)d_in[10];
  const float* msb  = (const float*)d_in[11];
  const float* mew  = (const float*)d_in[12];
  const float* meb  = (const float*)d_in[13];
  const float* s2eW = (const float*)d_in[14];
  const float* s2eb = (const float*)d_in[15];
  const float* csW  = (const float*)d_in[16];
  const float* csb  = (const float*)d_in[17];
  const float* csg  = (const float*)d_in[18];
  const float* csbe = (const float*)d_in[19];
  const float* ceW  = (const float*)d_in[20];
  const float* ceb  = (const float*)d_in[21];
  const float* ceg  = (const float*)d_in[22];
  const float* cebe = (const float*)d_in[23];
  const float* Ws2s = (const float*)d_in[24];
  const float* We2e = (const float*)d_in[25];
  const float* Ws2e = (const float*)d_in[26];
  const float* We2s = (const float*)d_in[27];
  const float* Bs2s = (const float*)d_in[28];
  const float* Be2e = (const float*)d_in[29];
  const float* Bs2e = (const float*)d_in[30];
  const float* Be2s = (const float*)d_in[31];
  float* outp = (float*)d_out;
  char* ws = (char*)d_ws;
  (void)in_sizes; (void)n_in; (void)out_size; (void)ws_size;

  // ---- workspace layout (liveness-aliased) ----
  // region X [0, 37748736): embsp3(25165824)+bse(12582912)
  //   reuse1: ssp3(25165824)+s2Wsp(6291456)
  //   reuse2: reps_s(4194304)+reps_e(4194304)+csWb(14680064)+ceWb(14680064)
  // region X+se also reused for Bbig(58720256) at offset 0 (after band & ce GEMM)
  const size_t o_embsp = 0;
  const size_t o_bse   = 25165824;
  const size_t o_ssp   = 0;
  const size_t o_s2W   = 25165824;
  const size_t o_repss = 0;
  const size_t o_repse = 4194304;
  const size_t o_csWb  = 8388608;
  const size_t o_ceWb  = 23068672;
  const size_t o_Bbig  = 0;
  const size_t o_se    = 37748736;   // 4096x2048 f32 = 33554432
  const size_t o_s2    = 71303168;   // 4096x1024 f32 = 16777216
  const size_t o_h     = 88080384;   // 2048x7168 f32 = 58720256 ; reused as Vcat bf16 [14][1024][2048]
  const size_t o_acat  = 146800640;  // 14x1024x2048 bf16 = 58720256
  const size_t o_smv   = 205520896;
  const size_t o_emv   = o_smv + 16384;
  const size_t o_band  = o_emv + 16384;
  const size_t o_starts= o_band + 524288;
  const size_t o_ends  = o_starts + 8192;
  const size_t o_tk    = o_ends + 8192;
  const size_t o_kv    = o_tk + 8192;
  const size_t o_biasv = o_kv + 256;

  __hip_bfloat16* embsp = (__hip_bfloat16*)(ws + o_embsp);
  __hip_bfloat16* bse   = (__hip_bfloat16*)(ws + o_bse);
  __hip_bfloat16* ssp   = (__hip_bfloat16*)(ws + o_ssp);
  __hip_bfloat16* s2Wsp = (__hip_bfloat16*)(ws + o_s2W);
  __hip_bfloat16* repss = (__hip_bfloat16*)(ws + o_repss);
  __hip_bfloat16* repse = (__hip_bfloat16*)(ws + o_repse);
  __hip_bfloat16* csWb  = (__hip_bfloat16*)(ws + o_csWb);
  __hip_bfloat16* ceWb  = (__hip_bfloat16*)(ws + o_ceWb);
  __hip_bfloat16* Bbig  = (__hip_bfloat16*)(ws + o_Bbig);
  float* se_buf = (float*)(ws + o_se);
  float* s2_buf = (float*)(ws + o_s2);
  float* h_buf  = (float*)(ws + o_h);
  __hip_bfloat16* Vcat  = (__hip_bfloat16*)(ws + o_h);
  __hip_bfloat16* a_cat = (__hip_bfloat16*)(ws + o_acat);
  float* smv_p = (float*)(ws + o_smv);
  float* emv_p = (float*)(ws + o_emv);
  float* band_p = (float*)(ws + o_band);
  int* starts_p = (int*)(ws + o_starts);
  int* ends_p = (int*)(ws + o_ends);
  float* tk_p = (float*)(ws + o_tk);
  int* kv_p = (int*)(ws + o_kv);
  float* biasv_p = (float*)(ws + o_biasv);

  // ---- stage A: se = [emb@smW^T | emb@emW^T] via split3 K-concat (f32-grade) ----
  k_packsplit3<true ><<<4096, 256, 0, stream>>>(x_emb, 1024, x_emb, 4096, embsp);
  k_packsplit3<false><<<2048, 256, 0, stream>>>(smW, 1024, emW, 1024, bse);
  k_gemm8<false, true><<<dim3(128, 1, 1), 512, 0, stream>>>(embsp, bse, se_buf, smb, embb,
      3072, 8, 0, 0, 0, 0, 2048, 4096, 2048);
  k_gelu_ln<<<4096, 256, 0, stream>>>(se_buf, 2048, 0, smg, smbe);
  k_gelu_ln<<<4096, 256, 0, stream>>>(se_buf, 2048, 1024, emg, embe);

  // ---- stage C: s2 = s@s2eW^T + b ; banded scores ----
  k_packsplit3<true ><<<4096, 256, 0, stream>>>(se_buf, 2048, se_buf, 4096, ssp);
  k_packsplit3<false><<<1024, 256, 0, stream>>>(s2eW, 1024, s2eW, 1024, s2Wsp);
  k_gemm8<false, false><<<dim3(64, 1, 1), 512, 0, stream>>>(ssp, s2Wsp, s2_buf, s2eb, nullptr,
      3072, 4, 0, 0, 0, 0, 1024, 4096, 1024);
  k_rowdot<<<1024, 256, 0, stream>>>(se_buf, 2048, 0, msw, msb, smv_p, 4096);
  k_rowdot<<<1024, 256, 0, stream>>>(se_buf, 2048, 1024, mew, meb, emv_p, 4096);
  k_band<<<4096, 256, 0, stream>>>(s2_buf, se_buf, smv_p, emv_p, band_p);

  // ---- stage D: exact top-k ----
  k_topk<<<2, 1024, 0, stream>>>(band_p, masks, starts_p, ends_p, tk_p, kv_p);

  // ---- stage E/F: gather + FC to per-category reps ----
  k_gather<<<2 * NK, 256, 0, stream>>>(x_emb, starts_p, ends_p, repss, repse);
  k_cast4<<<7168, 256, 0, stream>>>(csW, csWb, 1835008);
  k_cast4<<<7168, 256, 0, stream>>>(ceW, ceWb, 1835008);
  k_gemm8<false, false><<<dim3(224, 1, 1), 512, 0, stream>>>(repss, csWb, h_buf, csb, nullptr,
      1024, 28, 0, 0, 0, 0, 7168, 2048, 7168);
  k_gelu_ln_cats<<<2048, 256, 0, stream>>>(h_buf, csg, csbe, a_cat, 0);
  k_gemm8<false, false><<<dim3(224, 1, 1), 512, 0, stream>>>(repse, ceWb, h_buf, ceb, nullptr,
      1024, 28, 0, 0, 0, 0, 7168, 2048, 7168);
  k_packBbig<<<28672, 256, 0, stream>>>(Ws2s, We2e, Ws2e, We2s, Bbig);
  k_gelu_ln_cats<<<2048, 256, 0, stream>>>(h_buf, ceg, cebe, a_cat, 1);

  // ---- stage G: Vcat = a_cat @ Bbig^T (per z, cat = z%7), then logits ----
  k_gemm8<true, false><<<dim3(32, 1, Z_), 512, 0, stream>>>(a_cat, Bbig, Vcat, nullptr, nullptr,
      2048, 8, (long)NK * 2048, (long)2048 * 2048, 1, (long)NK * 2048, 2048, NK, 2048);
  k_bias<<<(Z_ * NK) / 4, 256, 0, stream>>>(a_cat, Bs2s, Be2e, Bs2e, Be2s, biasv_p);
  k_gemm8<false, false><<<dim3(16, 1, Z_), 512, 0, stream>>>(a_cat, Vcat, outp, nullptr, nullptr,
      2048, 4, (long)NK * 2048, (long)NK * 2048, 0, (long)MAXK * MAXK, MAXK, MAXK, MAXK);

  // ---- epilogue ----
  k_epi<<<(int)(((long)Z_ * MAXK * MAXK + 255) / 256), 256, 0, stream>>>(outp, biasv_p, tk_p, kv_p);
}

// Round 3
// 857.425 us; speedup vs baseline: 1.4647x; 1.0706x over previous
//
#include <hip/hip_runtime.h>
#include <hip/hip_bf16.h>
#include <math.h>

// ---- problem constants ----
#define S_    2048
#define NC_   7
#define MAXK  819
#define NK    1024          // padded top-k rows (4*256)
#define Z_    14            // B*NUM_CATS
#define NEGV  (-10000.0f)

typedef __attribute__((ext_vector_type(8))) short bf16x8;
typedef __attribute__((ext_vector_type(4))) float f32x4;

#define CFENCE asm volatile("" ::: "memory")
#define BAR    do { CFENCE; __builtin_amdgcn_s_barrier(); CFENCE; } while (0)

__device__ __forceinline__ void gload_lds16(const void* g, void* l) {
  __builtin_amdgcn_global_load_lds((const __attribute__((address_space(1))) unsigned int*)g,
                                   (__attribute__((address_space(3))) unsigned int*)l, 16, 0, 0);
}

__device__ __forceinline__ float gelu_exact(float x) {
  return 0.5f * x * (1.0f + erff(x * 0.70710678118654752f));
}
__device__ __forceinline__ unsigned short f2bf(float x) {
  __hip_bfloat16 h = __float2bfloat16(x);
  return *(unsigned short*)&h;
}
__device__ __forceinline__ float bf2f(unsigned short u) {
  __hip_bfloat16 h; *(unsigned short*)&h = u;
  return __bfloat162float(h);
}

// ============ 256x256 8-wave GEMM, BK=64, 8-phase counted-vmcnt pipeline ============
// C[m,n] = sum_k A[m,k]*B[n,k]  (both row-major with K inner)
// EPI 0: optional bias1[n]; EPI 1: bias1/bias2 split at n=1024; EPI 2: logits epilogue
template<bool OBF16, int EPI>
__global__ __launch_bounds__(512, 2) void k_gemm8(
    const __hip_bfloat16* __restrict__ A, const __hip_bfloat16* __restrict__ B,
    void* __restrict__ Cv, const float* __restrict__ bias1, const float* __restrict__ bias2,
    const float* __restrict__ tkv, const int* __restrict__ kvp,
    int K, int nbn, long strideA, long strideB, int bmod7, long strideC,
    int ldc, int Mstore, int Nstore)
{
  __shared__ __align__(16) char lds[2][65536];   // per buf: A[0,32K) B[32K,64K)
  const int tid = threadIdx.x;
  const int z = blockIdx.z;
  const int nwg = gridDim.x;
  const int xcd = blockIdx.x & 7, loc = blockIdx.x >> 3;
  const int q = nwg >> 3, r = nwg & 7;
  const int wg = (xcd < r ? xcd * (q + 1) : r * (q + 1) + (xcd - r) * q) + loc;
  const int bm = wg / nbn, bn = wg % nbn;
  const int m0 = bm * 256, n0 = bn * 256;
  const __hip_bfloat16* pA = A + (long)z * strideA;
  const __hip_bfloat16* pB = B + (long)(bmod7 ? (z % 7) : z) * strideB;
  const int wave = tid >> 6, lane = tid & 63;
  const int wm = wave >> 2, wn = wave & 3;
  const int lr = lane & 15, kh = lane >> 4;
  const long Kb = (long)K * 2;

  f32x4 acc[8][4];
  #pragma unroll
  for (int i = 0; i < 8; ++i)
    #pragma unroll
    for (int j = 0; j < 4; ++j)
      #pragma unroll
      for (int rr = 0; rr < 4; ++rr) acc[i][j][rr] = 0.0f;

  // stage one 16KB half-tile (rows rh*128..+127 of A or B) of K-tile kt into buf bb
  auto stageHalf = [&](int bb, int isB, int rh, int kt) {
    const __hip_bfloat16* src = isB ? pB : pA;
    const int base0 = isB ? n0 : m0;
    const long kbyte = (long)kt * 128;
    #pragma unroll
    for (int j = 0; j < 2; ++j) {
      int off = j * 8192 + tid * 16;
      int row = rh * 128 + (off >> 7);
      int col = off & 127;
      int gc = col ^ ((row & 7) << 4);          // inverse swizzle on global source
      gload_lds16((const char*)src + (long)(base0 + row) * Kb + kbyte + gc,
                  &lds[bb][isB * 32768 + row * 128 + col]);
    }
  };
  auto readA = [&](int c, int g, int kk) -> bf16x8 {
    int row = wm * 128 + g * 16 + lr;
    int colb = kk * 64 + kh * 16;
    return *(const bf16x8*)&lds[c][row * 128 + (colb ^ ((row & 7) << 4))];
  };
  auto readB = [&](int c, int ni, int kk) -> bf16x8 {
    int row = wn * 64 + ni * 16 + lr;
    int colb = kk * 64 + kh * 16;
    return *(const bf16x8*)&lds[c][32768 + row * 128 + (colb ^ ((row & 7) << 4))];
  };
  auto mfma4 = [&](int g0, bf16x8* af, bf16x8* bfr) {
    __builtin_amdgcn_s_setprio(1);
    #pragma unroll
    for (int mi = 0; mi < 4; ++mi)
      #pragma unroll
      for (int ni = 0; ni < 4; ++ni)
        acc[g0 + mi][ni] = __builtin_amdgcn_mfma_f32_16x16x32_bf16(af[mi], bfr[ni], acc[g0 + mi][ni], 0, 0, 0);
    __builtin_amdgcn_s_setprio(0);
  };

  const int nt = K >> 6;
  // prologue: B0(0) B1(0) A0(0) A1(0) [B0(1)]
  stageHalf(0, 1, 0, 0);
  stageHalf(0, 1, 1, 0);
  stageHalf(0, 0, 0, 0);
  stageHalf(0, 0, 1, 0);
  if (nt > 1) { stageHalf(1, 1, 0, 1); asm volatile("s_waitcnt vmcnt(2)" ::: "memory"); }
  else        { asm volatile("s_waitcnt vmcnt(0)" ::: "memory"); }
  BAR;

  bf16x8 bfr[4], a0f[4], a1f[4];
  for (int t = 0; t < nt; ++t) {
    const int c = t & 1, cn = c ^ 1;
    // ---- phase 0: B kk0 + A mi0-3 kk0 ; stage B1(t+1) ----
    #pragma unroll
    for (int i = 0; i < 4; ++i) bfr[i] = readB(c, i, 0);
    #pragma unroll
    for (int i = 0; i < 4; ++i) a0f[i] = readA(c, i, 0);
    if (t + 1 < nt) stageHalf(cn, 1, 1, t + 1);
    BAR;
    mfma4(0, a0f, bfr);
    BAR;
    // ---- phase 1: A mi4-7 kk0 ; stage A0(t+1) ----
    #pragma unroll
    for (int i = 0; i < 4; ++i) a1f[i] = readA(c, 4 + i, 0);
    if (t + 1 < nt) stageHalf(cn, 0, 0, t + 1);
    BAR;
    mfma4(4, a1f, bfr);
    BAR;
    // ---- phase 2: B kk1 + A mi0-3 kk1 ; stage A1(t+1) ----
    #pragma unroll
    for (int i = 0; i < 4; ++i) bfr[i] = readB(c, i, 1);
    #pragma unroll
    for (int i = 0; i < 4; ++i) a0f[i] = readA(c, i, 1);
    if (t + 1 < nt) stageHalf(cn, 0, 1, t + 1);
    BAR;
    mfma4(0, a0f, bfr);
    BAR;
    // ---- phase 3: A mi4-7 kk1 ; stage B0(t+2) ; counted vmcnt ----
    #pragma unroll
    for (int i = 0; i < 4; ++i) a1f[i] = readA(c, 4 + i, 1);
    if (t + 2 < nt) { stageHalf(c, 1, 0, t + 2); asm volatile("s_waitcnt vmcnt(2)" ::: "memory"); }
    else            { asm volatile("s_waitcnt vmcnt(0)" ::: "memory"); }
    BAR;
    mfma4(4, a1f, bfr);
    BAR;
  }

  const long coff = (long)z * strideC;
  int kval = 0, bb_ = 0;
  if (EPI == 2) { bb_ = z / NC_; kval = kvp[bb_]; }
  #pragma unroll
  for (int mi = 0; mi < 8; ++mi) {
    #pragma unroll
    for (int ni = 0; ni < 4; ++ni) {
      int n = n0 + wn * 64 + ni * 16 + lr;
      if (n >= Nstore) continue;
      float badd = 0.f;
      if (EPI == 0) { if (bias1) badd = bias1[n]; }
      if (EPI == 1) badd = (n >= 1024) ? bias2[n - 1024] : bias1[n];
      if (EPI == 2) badd = bias1[z * NK + n] + tkv[bb_ * NK + n];
      #pragma unroll
      for (int rr = 0; rr < 4; ++rr) {
        int m = m0 + wm * 128 + mi * 16 + kh * 4 + rr;
        if (m >= Mstore) continue;
        float v = acc[mi][ni][rr] + badd;
        if (EPI == 2) {
          v += tkv[bb_ * NK + m];
          if (!(n < m && n < kval)) v += NEGV;
        }
        if (OBF16) ((__hip_bfloat16*)Cv)[coff + (long)m * ldc + n] = __float2bfloat16(v);
        else       ((float*)Cv)[coff + (long)m * ldc + n] = v;
      }
    }
  }
}

// ---------- pack split3: dst rows 3072 wide. APAT: [hi|hi|lo]; else [hi|lo|hi] ----------
template<bool APAT>
__global__ __launch_bounds__(256) void k_packsplit3(const float* __restrict__ s1, long stride1,
                                                    const float* __restrict__ s2, int split,
                                                    __hip_bfloat16* __restrict__ dst) {
  long idx4 = ((long)blockIdx.x * 256 + threadIdx.x) * 4;
  int rrow = (int)(idx4 >> 10), c = (int)(idx4 & 1023);
  const float* src = (rrow < split) ? s1 + (long)rrow * stride1 + c
                                    : s2 + (long)(rrow - split) * 1024 + c;
  float4 v = *(const float4*)src;
  float f[4] = {v.x, v.y, v.z, v.w};
  unsigned short h[4], l4[4];
  #pragma unroll
  for (int i = 0; i < 4; ++i) {
    h[i] = f2bf(f[i]);
    l4[i] = f2bf(f[i] - bf2f(h[i]));
  }
  unsigned short* d = (unsigned short*)dst + (long)rrow * 3072;
  ushort4 hv = {h[0], h[1], h[2], h[3]};
  ushort4 lv = {l4[0], l4[1], l4[2], l4[3]};
  *(ushort4*)(d + c)        = hv;
  *(ushort4*)(d + 1024 + c) = APAT ? hv : lv;
  *(ushort4*)(d + 2048 + c) = APAT ? lv : hv;
}

// ---------- f32 -> bf16 vector cast ----------
__global__ __launch_bounds__(256) void k_cast4(const float* __restrict__ x,
                                               __hip_bfloat16* __restrict__ y, long n4) {
  long i = (long)blockIdx.x * 256 + threadIdx.x;
  if (i >= n4) return;
  float4 v = ((const float4*)x)[i];
  ushort4 o = {f2bf(v.x), f2bf(v.y), f2bf(v.z), f2bf(v.w)};
  ((ushort4*)y)[i] = o;
}

// ---------- pack Bbig[cat][n(2048)][k(2048)] from 4 weight tensors ----------
__global__ __launch_bounds__(256) void k_packBbig(const float* __restrict__ Ws2s,
                                                  const float* __restrict__ We2e,
                                                  const float* __restrict__ Ws2e,
                                                  const float* __restrict__ We2s,
                                                  __hip_bfloat16* __restrict__ dst) {
  long idx4 = ((long)blockIdx.x * 256 + threadIdx.x) * 4;
  long rowid = idx4 >> 11;
  int c = (int)(idx4 & 2047);
  int cat = (int)(rowid >> 11);
  int n = (int)(rowid & 2047);
  const float* src;
  if (n < 1024) src = (c < 1024) ? Ws2s + ((long)cat * 1024 + n) * 1024 + c
                                 : Ws2e + ((long)cat * 1024 + n) * 1024 + (c - 1024);
  else          src = (c < 1024) ? We2s + ((long)cat * 1024 + (n - 1024)) * 1024 + c
                                 : We2e + ((long)cat * 1024 + (n - 1024)) * 1024 + (c - 1024);
  float4 v = *(const float4*)src;
  ushort4 o = {f2bf(v.x), f2bf(v.y), f2bf(v.z), f2bf(v.w)};
  *(ushort4*)((unsigned short*)dst + idx4) = o;
}

// ---------- GELU + LayerNorm over 1024 cols, in-place f32, strided rows ----------
__global__ __launch_bounds__(256) void k_gelu_ln(float* __restrict__ h, long rowstride, int coff,
                                                 const float* __restrict__ g,
                                                 const float* __restrict__ beta) {
  long base = (long)blockIdx.x * rowstride + coff;
  float v[4];
  float s = 0.f, s2 = 0.f;
  #pragma unroll
  for (int i = 0; i < 4; ++i) {
    float x = h[base + i * 256 + threadIdx.x];
    float ge = gelu_exact(x);
    v[i] = ge; s += ge; s2 += ge * ge;
  }
  __shared__ float red0[4], red1[4];
  for (int off = 32; off; off >>= 1) { s += __shfl_xor(s, off); s2 += __shfl_xor(s2, off); }
  int w = threadIdx.x >> 6;
  if ((threadIdx.x & 63) == 0) { red0[w] = s; red1[w] = s2; }
  __syncthreads();
  s  = red0[0] + red0[1] + red0[2] + red0[3];
  s2 = red1[0] + red1[1] + red1[2] + red1[3];
  float mu  = s / 1024.0f;
  float var = s2 / 1024.0f - mu * mu;
  float inv = 1.0f / sqrtf(var + 1e-5f);
  #pragma unroll
  for (int i = 0; i < 4; ++i) {
    int c = i * 256 + threadIdx.x;
    h[base + c] = (v[i] - mu) * inv * g[c] + beta[c];
  }
}

// ---------- GELU+LN over 7168 (bf16 in), write bf16 into a_cat[z][k][2048] half ----------
__global__ __launch_bounds__(256) void k_gelu_ln_cats(const __hip_bfloat16* __restrict__ h,
                                                      const float* __restrict__ g,
                                                      const float* __restrict__ beta,
                                                      __hip_bfloat16* __restrict__ a_cat, int half) {
  int r = blockIdx.x;                       // 0..2047
  int b = r >> 10, k = r & 1023;
  const ushort4* row = (const ushort4*)((const unsigned short*)h + (long)r * 7168);
  float v[28];
  float s = 0.f, s2 = 0.f;
  #pragma unroll
  for (int j = 0; j < 7; ++j) {
    ushort4 u = row[threadIdx.x + 256 * j];
    #pragma unroll
    for (int e = 0; e < 4; ++e) {
      float x = bf2f(((const unsigned short*)&u)[e]);
      float ge = gelu_exact(x);
      v[j * 4 + e] = ge; s += ge; s2 += ge * ge;
    }
  }
  __shared__ float red0[4], red1[4];
  for (int off = 32; off; off >>= 1) { s += __shfl_xor(s, off); s2 += __shfl_xor(s2, off); }
  int w = threadIdx.x >> 6;
  if ((threadIdx.x & 63) == 0) { red0[w] = s; red1[w] = s2; }
  __syncthreads();
  s  = red0[0] + red0[1] + red0[2] + red0[3];
  s2 = red1[0] + red1[1] + red1[2] + red1[3];
  float mu  = s / 7168.0f;
  float var = s2 / 7168.0f - mu * mu;
  float inv = 1.0f / sqrtf(var + 1e-5f);
  #pragma unroll
  for (int j = 0; j < 7; ++j) {
    int c0 = (threadIdx.x + 256 * j) * 4;
    int n = c0 >> 10, f = c0 & 1023;
    unsigned short o[4];
    #pragma unroll
    for (int e = 0; e < 4; ++e)
      o[e] = f2bf((v[j * 4 + e] - mu) * inv * g[c0 + e] + beta[c0 + e]);
    ushort4 ov = {o[0], o[1], o[2], o[3]};
    *(ushort4*)((unsigned short*)a_cat + ((long)((b * NC_ + n) * NK + k)) * 2048 + half * 1024 + f) = ov;
  }
}

// ---------- row dot: out[r] = X[r,:1024].w + b0 ----------
__global__ __launch_bounds__(256) void k_rowdot(const float* __restrict__ X, long rowstride, int coff,
                                                const float* __restrict__ wv,
                                                const float* __restrict__ b0,
                                                float* __restrict__ outp, int rows) {
  int w = threadIdx.x >> 6, l = threadIdx.x & 63;
  int row = blockIdx.x * 4 + w;
  if (row >= rows) return;
  const float4* xp = (const float4*)(X + (long)row * rowstride + coff);
  const float4* wp = (const float4*)wv;
  float acc = 0.f;
  #pragma unroll
  for (int qq = 0; qq < 4; ++qq) {
    float4 a = xp[l + 64 * qq], b = wp[l + 64 * qq];
    acc += a.x * b.x + a.y * b.y + a.z * b.z + a.w * b.w;
  }
  for (int off = 32; off; off >>= 1) acc += __shfl_xor(acc, off);
  if (l == 0) outp[row] = acc + b0[0];
}

// ---------- banded scores ----------
__global__ __launch_bounds__(256) void k_band(const float* __restrict__ s2m,
                                              const float* __restrict__ se,
                                              const float* __restrict__ smv,
                                              const float* __restrict__ emv,
                                              float* __restrict__ band) {
  __shared__ float s2row[1024];
  int bs = blockIdx.x;                 // b*2048+s
  const float* sp = s2m + (long)bs * 1024;
  for (int i = threadIdx.x; i < 1024; i += 256) s2row[i] = sp[i];
  __syncthreads();
  int b = bs >> 11, s = bs & 2047;
  int w = threadIdx.x >> 6, l = threadIdx.x & 63;
  for (int j = w; j < 32; j += 4) {
    int t = s + j;
    float val = -3.0e38f;
    if (j < 30 && t < S_) {
      const float4* ep = (const float4*)(se + ((long)((b << 11) + t)) * 2048 + 1024);
      const float4* zp = (const float4*)s2row;
      float acc = 0.f;
      #pragma unroll
      for (int qq = 0; qq < 4; ++qq) {
        float4 a = ep[l + 64 * qq], c = zp[l + 64 * qq];
        acc += a.x * c.x + a.y * c.y + a.z * c.z + a.w * c.w;
      }
      for (int off = 32; off; off >>= 1) acc += __shfl_xor(acc, off);
      val = acc + smv[bs] + emv[(b << 11) + t];
    }
    if (l == 0) band[(long)bs * 32 + j] = val;
  }
}

// ---------- exact top-k (radix select + bitonic), one block per batch ----------
__device__ __forceinline__ void bitonic1024(unsigned* buf) {
  int tid = threadIdx.x;
  __syncthreads();
  for (int k = 2; k <= 1024; k <<= 1)
    for (int j = k >> 1; j > 0; j >>= 1) {
      int ixj = tid ^ j;
      if (ixj > tid) {
        unsigned a = buf[tid], c = buf[ixj];
        bool up = ((tid & k) == 0);
        if (up ? (a > c) : (a < c)) { buf[tid] = c; buf[ixj] = a; }
      }
      __syncthreads();
    }
}

__global__ __launch_bounds__(1024) void k_topk(const float* __restrict__ band,
                                               const int* __restrict__ masks,
                                               int* __restrict__ starts, int* __restrict__ ends,
                                               float* __restrict__ tk, int* __restrict__ kvalid_out) {
  int b = blockIdx.x;
  const float* bb = band + (long)b * 65536;
  __shared__ unsigned hist[256];
  __shared__ int sh_digit, sh_R, sh_msum;
  __shared__ unsigned cntG, cntE;
  __shared__ unsigned listG[832];
  __shared__ unsigned listE[1024];
  __shared__ unsigned buf[1024];
  int tid = threadIdx.x;

  if (tid == 0) sh_msum = 0;
  __syncthreads();
  int pm = masks[b * S_ + tid] + masks[b * S_ + 1024 + tid];
  atomicAdd(&sh_msum, pm);
  __syncthreads();
  int kv = (int)((float)sh_msum * 0.4f);
  if (kv > MAXK) kv = MAXK;

  unsigned prefix = 0;
  int R = kv;
  if (kv > 0) {
    for (int shift = 24; shift >= 0; shift -= 8) {
      if (tid < 256) hist[tid] = 0;
      __syncthreads();
      for (int i = tid; i < 65536; i += 1024) {
        unsigned u = __float_as_uint(bb[i]);
        unsigned key = (u & 0x80000000u) ? ~u : (u | 0x80000000u);
        bool ok = (shift == 24) || ((key >> (shift + 8)) == (prefix >> (shift + 8)));
        if (ok) atomicAdd(&hist[(key >> shift) & 255u], 1u);
      }
      __syncthreads();
      if (tid == 0) {
        unsigned cum = 0; int d;
        for (d = 255; d >= 0; --d) {
          unsigned hc = hist[d];
          if (cum + hc >= (unsigned)R) break;
          cum += hc;
        }
        if (d < 0) d = 0;
        sh_digit = d; sh_R = R - (int)cum;
      }
      __syncthreads();
      prefix |= ((unsigned)sh_digit) << shift;
      R = sh_R;
      __syncthreads();
    }
  }
  if (tid == 0) { cntG = 0; cntE = 0; }
  __syncthreads();
  if (kv > 0) {
    for (int i = tid; i < 65536; i += 1024) {
      unsigned u = __float_as_uint(bb[i]);
      unsigned key = (u & 0x80000000u) ? ~u : (u | 0x80000000u);
      if (key > prefix) { unsigned p = atomicAdd(&cntG, 1u); if (p < 832) listG[p] = (unsigned)i; }
      else if (key == prefix) { unsigned p = atomicAdd(&cntE, 1u); if (p < 1024) listE[p] = (unsigned)i; }
    }
  }
  __syncthreads();
  int nG = (int)cntG, nE = (int)cntE, need = R;
  buf[tid] = (tid < nE) ? listE[tid] : 0xFFFFFFFFu;
  bitonic1024(buf);
  if (tid < need) listG[nG + tid] = buf[tid];
  __syncthreads();
  unsigned v2 = (tid < (unsigned)kv) ? listG[tid] : 0xFFFFFFFFu;
  __syncthreads();
  buf[tid] = v2;
  bitonic1024(buf);
  {
    int s, t; float val;
    if (tid < kv) {
      unsigned i = buf[tid];
      s = (int)(i >> 5); t = s + (int)(i & 31);
      val = bb[i];
    } else {
      s = S_ - 1; t = S_ - 1;
      val = bb[(S_ - 1) * 32 + 0];
    }
    starts[b * NK + tid] = s;
    ends[b * NK + tid] = t;
    tk[b * NK + tid] = val;
  }
  if (tid == 0) kvalid_out[b] = kv;
}

// ---------- gather span reps to bf16 ----------
__global__ __launch_bounds__(256) void k_gather(const float* __restrict__ emb,
                                                const int* __restrict__ starts,
                                                const int* __restrict__ ends,
                                                __hip_bfloat16* __restrict__ reps_s,
                                                __hip_bfloat16* __restrict__ reps_e) {
  int r = blockIdx.x;                 // b*NK + k
  int b = r >> 10;
  long ob = (long)r * 1024;
  const float4* ps = (const float4*)(emb + ((long)b * S_ + starts[r]) * 1024);
  const float4* pe = (const float4*)(emb + ((long)b * S_ + ends[r]) * 1024);
  unsigned short* ds = (unsigned short*)reps_s + ob;
  unsigned short* de = (unsigned short*)reps_e + ob;
  int c4 = threadIdx.x;
  float4 a = ps[c4], e = pe[c4];
  ushort4 oa = {f2bf(a.x), f2bf(a.y), f2bf(a.z), f2bf(a.w)};
  ushort4 oe = {f2bf(e.x), f2bf(e.y), f2bf(e.z), f2bf(e.w)};
  *(ushort4*)(ds + c4 * 4) = oa;
  *(ushort4*)(de + c4 * 4) = oe;
}

// ---------- antecedent bias vector (reads a_cat) ----------
__global__ __launch_bounds__(256) void k_bias(const __hip_bfloat16* __restrict__ a_cat,
                                              const float* __restrict__ Bs2s, const float* __restrict__ Be2e,
                                              const float* __restrict__ Bs2e, const float* __restrict__ Be2s,
                                              float* __restrict__ biasv) {
  int w = threadIdx.x >> 6, l = threadIdx.x & 63;
  int row = blockIdx.x * 4 + w;       // z*NK + lidx
  if (row >= Z_ * NK) return;
  int z = row >> 10, cat = z % NC_;
  const unsigned short* ar = (const unsigned short*)a_cat + (long)row * 2048;
  const float* b1 = Bs2s + cat * 1024;
  const float* b2 = Be2s + cat * 1024;
  const float* b3 = Be2e + cat * 1024;
  const float* b4 = Bs2e + cat * 1024;
  float acc = 0.f;
  for (int qq = 0; qq < 16; ++qq) {
    int c = l + 64 * qq;
    acc += bf2f(ar[c]) * (b1[c] + b2[c]);
    acc += bf2f(ar[1024 + c]) * (b3[c] + b4[c]);
  }
  for (int off = 32; off; off >>= 1) acc += __shfl_xor(acc, off);
  if (l == 0) biasv[row] = acc;
}

// =====================================================================
extern "C" void kernel_launch(void* const* d_in, const int* in_sizes, int n_in,
                              void* d_out, int out_size, void* d_ws, size_t ws_size,
                              hipStream_t stream) {
  const float* x_emb = (const float*)d_in[0];
  const int*   masks = (const int*)d_in[1];
  const float* smW  = (const float*)d_in[2];
  const float* smb  = (const float*)d_in[3];
  const float* smg  = (const float*)d_in[4];
  const float* smbe = (const float*)d_in[5];
  const float* emW  = (const float*)d_in[6];
  const float* embb = (const float*)d_in[7];
  const float* emg  = (const float*)d_in[8];
  const float* embe = (const float*)d_in[9];
  const float* msw  = (const float*)d_in[10];
  const float* msb  = (const float*)d_in[11];
  const float* mew  = (const float*)d_in[12];
  const float* meb  = (const float*)d_in[13];
  const float* s2eW = (const float*)d_in[14];
  const float* s2eb = (const float*)d_in[15];
  const float* csW  = (const float*)d_in[16];
  const float* csb  = (const float*)d_in[17];
  const float* csg  = (const float*)d_in[18];
  const float* csbe = (const float*)d_in[19];
  const float* ceW  = (const float*)d_in[20];
  const float* ceb  = (const float*)d_in[21];
  const float* ceg  = (const float*)d_in[22];
  const float* cebe = (const float*)d_in[23];
  const float* Ws2s = (const float*)d_in[24];
  const float* We2e = (const float*)d_in[25];
  const float* Ws2e = (const float*)d_in[26];
  const float* We2s = (const float*)d_in[27];
  const float* Bs2s = (const float*)d_in[28];
  const float* Be2e = (const float*)d_in[29];
  const float* Bs2e = (const float*)d_in[30];
  const float* Be2s = (const float*)d_in[31];
  float* outp = (float*)d_out;
  char* ws = (char*)d_ws;
  (void)in_sizes; (void)n_in; (void)out_size; (void)ws_size;

  // ---- workspace layout (liveness-aliased) ----
  const size_t o_embsp = 0;
  const size_t o_bse   = 25165824;
  const size_t o_ssp   = 0;
  const size_t o_s2W   = 25165824;
  const size_t o_repss = 0;
  const size_t o_repse = 4194304;
  const size_t o_csWb  = 8388608;
  const size_t o_ceWb  = 23068672;
  const size_t o_Bbig  = 0;
  const size_t o_se    = 37748736;   // 4096x2048 f32 = 33554432
  const size_t o_s2    = 71303168;   // 4096x1024 f32 = 16777216
  const size_t o_h     = 88080384;   // 2048x7168 bf16 = 29360128 ; later Vcat bf16 [14][1024][2048]
  const size_t o_acat  = 146800640;  // 14x1024x2048 bf16 = 58720256
  const size_t o_smv   = 205520896;
  const size_t o_emv   = o_smv + 16384;
  const size_t o_band  = o_emv + 16384;
  const size_t o_starts= o_band + 524288;
  const size_t o_ends  = o_starts + 8192;
  const size_t o_tk    = o_ends + 8192;
  const size_t o_kv    = o_tk + 8192;
  const size_t o_biasv = o_kv + 256;

  __hip_bfloat16* embsp = (__hip_bfloat16*)(ws + o_embsp);
  __hip_bfloat16* bse   = (__hip_bfloat16*)(ws + o_bse);
  __hip_bfloat16* ssp   = (__hip_bfloat16*)(ws + o_ssp);
  __hip_bfloat16* s2Wsp = (__hip_bfloat16*)(ws + o_s2W);
  __hip_bfloat16* repss = (__hip_bfloat16*)(ws + o_repss);
  __hip_bfloat16* repse = (__hip_bfloat16*)(ws + o_repse);
  __hip_bfloat16* csWb  = (__hip_bfloat16*)(ws + o_csWb);
  __hip_bfloat16* ceWb  = (__hip_bfloat16*)(ws + o_ceWb);
  __hip_bfloat16* Bbig  = (__hip_bfloat16*)(ws + o_Bbig);
  float* se_buf = (float*)(ws + o_se);
  float* s2_buf = (float*)(ws + o_s2);
  __hip_bfloat16* h_buf = (__hip_bfloat16*)(ws + o_h);
  __hip_bfloat16* Vcat  = (__hip_bfloat16*)(ws + o_h);
  __hip_bfloat16* a_cat = (__hip_bfloat16*)(ws + o_acat);
  float* smv_p = (float*)(ws + o_smv);
  float* emv_p = (float*)(ws + o_emv);
  float* band_p = (float*)(ws + o_band);
  int* starts_p = (int*)(ws + o_starts);
  int* ends_p = (int*)(ws + o_ends);
  float* tk_p = (float*)(ws + o_tk);
  int* kv_p = (int*)(ws + o_kv);
  float* biasv_p = (float*)(ws + o_biasv);

  // ---- stage A: se = [emb@smW^T | emb@emW^T] via split3 K-concat (f32-grade) ----
  k_packsplit3<true ><<<4096, 256, 0, stream>>>(x_emb, 1024, x_emb, 4096, embsp);
  k_packsplit3<false><<<2048, 256, 0, stream>>>(smW, 1024, emW, 1024, bse);
  k_gemm8<false, 1><<<dim3(128, 1, 1), 512, 0, stream>>>(embsp, bse, se_buf, smb, embb,
      nullptr, nullptr, 3072, 8, 0, 0, 0, 0, 2048, 4096, 2048);
  k_gelu_ln<<<4096, 256, 0, stream>>>(se_buf, 2048, 0, smg, smbe);
  k_gelu_ln<<<4096, 256, 0, stream>>>(se_buf, 2048, 1024, emg, embe);

  // ---- stage C: s2 = s@s2eW^T + b ; banded scores ----
  k_packsplit3<true ><<<4096, 256, 0, stream>>>(se_buf, 2048, se_buf, 4096, ssp);
  k_packsplit3<false><<<1024, 256, 0, stream>>>(s2eW, 1024, s2eW, 1024, s2Wsp);
  k_gemm8<false, 0><<<dim3(64, 1, 1), 512, 0, stream>>>(ssp, s2Wsp, s2_buf, s2eb, nullptr,
      nullptr, nullptr, 3072, 4, 0, 0, 0, 0, 1024, 4096, 1024);
  k_rowdot<<<1024, 256, 0, stream>>>(se_buf, 2048, 0, msw, msb, smv_p, 4096);
  k_rowdot<<<1024, 256, 0, stream>>>(se_buf, 2048, 1024, mew, meb, emv_p, 4096);
  k_band<<<4096, 256, 0, stream>>>(s2_buf, se_buf, smv_p, emv_p, band_p);

  // ---- stage D: exact top-k ----
  k_topk<<<2, 1024, 0, stream>>>(band_p, masks, starts_p, ends_p, tk_p, kv_p);

  // ---- stage E/F: gather + FC to per-category reps ----
  k_gather<<<2 * NK, 256, 0, stream>>>(x_emb, starts_p, ends_p, repss, repse);
  k_cast4<<<7168, 256, 0, stream>>>(csW, csWb, 1835008);
  k_cast4<<<7168, 256, 0, stream>>>(ceW, ceWb, 1835008);
  k_gemm8<true, 0><<<dim3(224, 1, 1), 512, 0, stream>>>(repss, csWb, h_buf, csb, nullptr,
      nullptr, nullptr, 1024, 28, 0, 0, 0, 0, 7168, 2048, 7168);
  k_gelu_ln_cats<<<2048, 256, 0, stream>>>(h_buf, csg, csbe, a_cat, 0);
  k_gemm8<true, 0><<<dim3(224, 1, 1), 512, 0, stream>>>(repse, ceWb, h_buf, ceb, nullptr,
      nullptr, nullptr, 1024, 28, 0, 0, 0, 0, 7168, 2048, 7168);
  k_packBbig<<<28672, 256, 0, stream>>>(Ws2s, We2e, Ws2e, We2s, Bbig);
  k_gelu_ln_cats<<<2048, 256, 0, stream>>>(h_buf, ceg, cebe, a_cat, 1);

  // ---- stage G: Vcat = a_cat @ Bbig^T (per z, cat = z%7), then logits ----
  k_gemm8<true, 0><<<dim3(32, 1, Z_), 512, 0, stream>>>(a_cat, Bbig, Vcat, nullptr, nullptr,
      nullptr, nullptr, 2048, 8, (long)NK * 2048, (long)2048 * 2048, 1, (long)NK * 2048, 2048, NK, 2048);
  k_bias<<<(Z_ * NK) / 4, 256, 0, stream>>>(a_cat, Bs2s, Be2e, Bs2e, Be2s, biasv_p);
  // logits + fused epilogue (bias[l] + pair + mask) straight into d_out
  k_gemm8<false, 2><<<dim3(16, 1, Z_), 512, 0, stream>>>(a_cat, Vcat, outp, biasv_p, nullptr,
      tk_p, kv_p, 2048, 4, (long)NK * 2048, (long)NK * 2048, 0, (long)MAXK * MAXK, MAXK, MAXK, MAXK);
}